// Round 1
// baseline (230.675 us; speedup 1.0000x reference)
//
#include <hip/hip_runtime.h>

#define IN_F 256
#define OU_F 64

// hp = h @ W  (fp32). Block = 256 threads = 4 waves.
// Thread (f = tid&63, kq = tid>>6) keeps W[kq*64 .. kq*64+63][f] in 64 VGPRs.
// 16 rows of h staged in LDS per iteration; reads are wave-uniform float4
// broadcasts (conflict-free). 4 k-partials reduced through LDS.
__global__ void __launch_bounds__(256, 4)
gemm_kernel(const float* __restrict__ h, const float* __restrict__ W,
            float* __restrict__ hp, int N)
{
    __shared__ float hs[16][IN_F];        // 16 KB
    __shared__ float ps[4][16][OU_F];     // 16 KB partials
    const int tid = threadIdx.x;
    const int f   = tid & 63;
    const int kq  = tid >> 6;

    float w[64];
#pragma unroll
    for (int j = 0; j < 64; ++j)
        w[j] = W[(kq * 64 + j) * OU_F + f];      // coalesced across f

    for (int r0 = blockIdx.x * 16; r0 < N; r0 += gridDim.x * 16) {
        // stage 16 rows x 256 floats, fully coalesced (1 KB per wave instr)
#pragma unroll
        for (int q = 0; q < 4; ++q) {
            int idx = tid + q * 256;              // 0..1023 float4 slots
            int r = idx >> 6, c4 = idx & 63;
            float4 v = make_float4(0.f, 0.f, 0.f, 0.f);
            if (r0 + r < N)
                v = reinterpret_cast<const float4*>(h)[(size_t)(r0 + r) * (IN_F / 4) + c4];
            reinterpret_cast<float4*>(&hs[r][0])[c4] = v;
        }
        __syncthreads();

        float acc[16];
#pragma unroll
        for (int r = 0; r < 16; ++r) acc[r] = 0.f;

#pragma unroll
        for (int j4 = 0; j4 < 16; ++j4) {
            const float wx = w[j4 * 4 + 0], wy = w[j4 * 4 + 1];
            const float wz = w[j4 * 4 + 2], ww = w[j4 * 4 + 3];
#pragma unroll
            for (int r = 0; r < 16; ++r) {
                float4 hv = *reinterpret_cast<const float4*>(&hs[r][kq * 64 + j4 * 4]);
                acc[r] = fmaf(hv.x, wx, acc[r]);
                acc[r] = fmaf(hv.y, wy, acc[r]);
                acc[r] = fmaf(hv.z, wz, acc[r]);
                acc[r] = fmaf(hv.w, ww, acc[r]);
            }
        }

#pragma unroll
        for (int r = 0; r < 16; ++r) ps[kq][r][f] = acc[r];   // conflict-free
        __syncthreads();

        // reduce the 4 k-partials; 1024 outputs, 4 per thread, coalesced store
#pragma unroll
        for (int q = 0; q < 4; ++q) {
            int e = tid + q * 256;
            int r = e >> 6, ff = e & 63;
            if (r0 + r < N)
                hp[(size_t)(r0 + r) * OU_F + ff] =
                    ps[0][r][ff] + ps[1][r][ff] + ps[2][r][ff] + ps[3][r][ff];
        }
        // no third barrier needed: next hs-write happens only after all
        // threads passed the ps-barrier (hs reads of this iter are done),
        // and next ps-write happens only after the next hs-barrier.
    }
}

// One lane per (edge, feature): out[col[e]][f] += vals[e] * hp[row[e]][f]
__global__ void __launch_bounds__(256)
scatter_kernel(const float* __restrict__ hp, const int* __restrict__ row,
               const int* __restrict__ col, const float* __restrict__ vals,
               float* __restrict__ out, int E)
{
    unsigned int gid = blockIdx.x * 256u + threadIdx.x;
    int e = (int)(gid >> 6);
    if (e >= E) return;
    int f = (int)(gid & 63u);
    int r = row[e], c = col[e];
    float v = vals[e];
    float m = v * hp[(size_t)r * OU_F + f];        // coalesced 256B gather
    __hip_atomic_fetch_add(&out[(size_t)c * OU_F + f], m,
                           __ATOMIC_RELAXED, __HIP_MEMORY_SCOPE_AGENT);
}

extern "C" void kernel_launch(void* const* d_in, const int* in_sizes, int n_in,
                              void* d_out, int out_size, void* d_ws, size_t ws_size,
                              hipStream_t stream)
{
    const float* h    = (const float*)d_in[0];
    const float* W    = (const float*)d_in[1];
    const int*   row  = (const int*)d_in[2];
    const int*   col  = (const int*)d_in[3];
    const float* vals = (const float*)d_in[4];
    float*       out  = (float*)d_out;

    const int N = in_sizes[0] / IN_F;
    const int E = in_sizes[2];

    float* hp = (float*)d_ws;                    // N*64 fp32 = 12.8 MB scratch

    // out is accumulated via atomics -> must be zeroed every call
    hipMemsetAsync(d_out, 0, (size_t)out_size * sizeof(float), stream);

    gemm_kernel<<<1024, 256, 0, stream>>>(h, W, hp, N);

    unsigned long long total = (unsigned long long)E * 64ull;
    unsigned int sgrid = (unsigned int)((total + 255ull) / 256ull);
    scatter_kernel<<<sgrid, 256, 0, stream>>>(hp, row, col, vals, out, E);
}

// Round 2
// 173.426 us; speedup vs baseline: 1.3301x; 1.3301x over previous
//
#include <hip/hip_runtime.h>

#define IN_F 256
#define OU_F 64

// ---------------- GEMM: hp = h @ W (fp32, unchanged from round 1) ----------------
__global__ void __launch_bounds__(256, 4)
gemm_kernel(const float* __restrict__ h, const float* __restrict__ W,
            float* __restrict__ hp, int N)
{
    __shared__ float hs[16][IN_F];
    __shared__ float ps[4][16][OU_F];
    const int tid = threadIdx.x;
    const int f   = tid & 63;
    const int kq  = tid >> 6;

    float w[64];
#pragma unroll
    for (int j = 0; j < 64; ++j)
        w[j] = W[(kq * 64 + j) * OU_F + f];

    for (int r0 = blockIdx.x * 16; r0 < N; r0 += gridDim.x * 16) {
#pragma unroll
        for (int q = 0; q < 4; ++q) {
            int idx = tid + q * 256;
            int r = idx >> 6, c4 = idx & 63;
            float4 v = make_float4(0.f, 0.f, 0.f, 0.f);
            if (r0 + r < N)
                v = reinterpret_cast<const float4*>(h)[(size_t)(r0 + r) * (IN_F / 4) + c4];
            reinterpret_cast<float4*>(&hs[r][0])[c4] = v;
        }
        __syncthreads();

        float acc[16];
#pragma unroll
        for (int r = 0; r < 16; ++r) acc[r] = 0.f;

#pragma unroll
        for (int j4 = 0; j4 < 16; ++j4) {
            const float wx = w[j4 * 4 + 0], wy = w[j4 * 4 + 1];
            const float wz = w[j4 * 4 + 2], ww = w[j4 * 4 + 3];
#pragma unroll
            for (int r = 0; r < 16; ++r) {
                float4 hv = *reinterpret_cast<const float4*>(&hs[r][kq * 64 + j4 * 4]);
                acc[r] = fmaf(hv.x, wx, acc[r]);
                acc[r] = fmaf(hv.y, wy, acc[r]);
                acc[r] = fmaf(hv.z, wz, acc[r]);
                acc[r] = fmaf(hv.w, ww, acc[r]);
            }
        }

#pragma unroll
        for (int r = 0; r < 16; ++r) ps[kq][r][f] = acc[r];
        __syncthreads();

#pragma unroll
        for (int q = 0; q < 4; ++q) {
            int e = tid + q * 256;
            int r = e >> 6, ff = e & 63;
            if (r0 + r < N)
                hp[(size_t)(r0 + r) * OU_F + ff] =
                    ps[0][r][ff] + ps[1][r][ff] + ps[2][r][ff] + ps[3][r][ff];
        }
    }
}

// ---------------- CSR build: histogram -> scan -> fill ----------------
__global__ void __launch_bounds__(256)
hist_kernel(const int* __restrict__ col, int* __restrict__ cnt, int E)
{
    for (int e = blockIdx.x * 256 + threadIdx.x; e < E; e += gridDim.x * 256)
        atomicAdd(&cnt[col[e]], 1);
}

// per-block (1024-element chunk) sums
__global__ void __launch_bounds__(256)
scanA_kernel(const int* __restrict__ cnt, int* __restrict__ part, int N)
{
    __shared__ int red[256];
    int idx = blockIdx.x * 1024 + threadIdx.x * 4;
    int s = 0;
    if (idx + 3 < N) {
        int4 v = *reinterpret_cast<const int4*>(&cnt[idx]);
        s = v.x + v.y + v.z + v.w;
    } else {
        for (int k = 0; k < 4; ++k) if (idx + k < N) s += cnt[idx + k];
    }
    red[threadIdx.x] = s;
    __syncthreads();
    for (int d = 128; d > 0; d >>= 1) {
        if (threadIdx.x < d) red[threadIdx.x] += red[threadIdx.x + d];
        __syncthreads();
    }
    if (threadIdx.x == 0) part[blockIdx.x] = red[0];
}

// exclusive scan of the (<=64) block partials in one wave
__global__ void __launch_bounds__(64)
scanB_kernel(int* __restrict__ part, int* __restrict__ offs, int nb, int N, int E)
{
    int lane = threadIdx.x;
    if (nb <= 64) {
        int orig = (lane < nb) ? part[lane] : 0;
        int v = orig;
        for (int d = 1; d < 64; d <<= 1) {
            int u = __shfl_up(v, d);
            if (lane >= d) v += u;
        }
        if (lane < nb) part[lane] = v - orig;   // exclusive
    } else if (lane == 0) {
        int run = 0;
        for (int i = 0; i < nb; ++i) { int t = part[i]; part[i] = run; run += t; }
    }
    if (lane == 0) offs[N] = E;
}

// per-chunk exclusive scan + block base -> offsets, and a working copy (cursor)
__global__ void __launch_bounds__(256)
scanC_kernel(const int* __restrict__ cnt, const int* __restrict__ part,
             int* __restrict__ offs, int* __restrict__ cursor, int N)
{
    __shared__ int lds[256];
    int tid = threadIdx.x;
    int idx = blockIdx.x * 1024 + tid * 4;
    int c0 = 0, c1 = 0, c2 = 0, c3 = 0;
    if (idx + 3 < N) {
        int4 v = *reinterpret_cast<const int4*>(&cnt[idx]);
        c0 = v.x; c1 = v.y; c2 = v.z; c3 = v.w;
    } else {
        if (idx     < N) c0 = cnt[idx];
        if (idx + 1 < N) c1 = cnt[idx + 1];
        if (idx + 2 < N) c2 = cnt[idx + 2];
        if (idx + 3 < N) c3 = cnt[idx + 3];
    }
    int s0 = c0, s1 = s0 + c1, s2 = s1 + c2, s3 = s2 + c3;
    lds[tid] = s3;
    __syncthreads();
    for (int d = 1; d < 256; d <<= 1) {            // Hillis-Steele inclusive
        int v = (tid >= d) ? lds[tid - d] : 0;
        __syncthreads();
        lds[tid] += v;
        __syncthreads();
    }
    int excl = (tid ? lds[tid - 1] : 0) + part[blockIdx.x];
    int o0 = excl, o1 = excl + s0, o2 = excl + s1, o3 = excl + s2;
    if (idx + 3 < N) {
        int4 o = make_int4(o0, o1, o2, o3);
        *reinterpret_cast<int4*>(&offs[idx])   = o;
        *reinterpret_cast<int4*>(&cursor[idx]) = o;
    } else {
        if (idx     < N) { offs[idx]     = o0; cursor[idx]     = o0; }
        if (idx + 1 < N) { offs[idx + 1] = o1; cursor[idx + 1] = o1; }
        if (idx + 2 < N) { offs[idx + 2] = o2; cursor[idx + 2] = o2; }
        if (idx + 3 < N) { offs[idx + 3] = o3; cursor[idx + 3] = o3; }
    }
}

__global__ void __launch_bounds__(256)
fill_kernel(const int* __restrict__ row, const int* __restrict__ col,
            const float* __restrict__ vals, int* __restrict__ cursor,
            int* __restrict__ erow, float* __restrict__ eval_, int E)
{
    for (int e = blockIdx.x * 256 + threadIdx.x; e < E; e += gridDim.x * 256) {
        int c = col[e];
        int p = atomicAdd(&cursor[c], 1);
        erow[p] = row[e];
        eval_[p] = vals[e];
    }
}

// ---------------- Gather: one wave per destination node, no atomics ----------------
__global__ void __launch_bounds__(256)
gather_kernel(const float* __restrict__ hp, const int* __restrict__ offs,
              const int* __restrict__ erow, const float* __restrict__ eval_,
              float* __restrict__ out, int N)
{
    int wid  = (int)((blockIdx.x * 256u + threadIdx.x) >> 6);   // node id
    int lane = threadIdx.x & 63;                                 // feature id
    if (wid >= N) return;
    int s = offs[wid], e = offs[wid + 1];
    float acc = 0.f;
    for (int base = s; base < e; base += 64) {
        int n = min(64, e - base);
        int er = 0; float ev = 0.f;
        if (lane < n) { er = erow[base + lane]; ev = eval_[base + lane]; }
        int j = 0;
        for (; j + 4 <= n; j += 4) {
            int   r0 = __shfl(er, j),     r1 = __shfl(er, j + 1);
            int   r2 = __shfl(er, j + 2), r3 = __shfl(er, j + 3);
            float v0 = __shfl(ev, j),     v1 = __shfl(ev, j + 1);
            float v2 = __shfl(ev, j + 2), v3 = __shfl(ev, j + 3);
            float x0 = hp[(size_t)r0 * OU_F + lane];
            float x1 = hp[(size_t)r1 * OU_F + lane];
            float x2 = hp[(size_t)r2 * OU_F + lane];
            float x3 = hp[(size_t)r3 * OU_F + lane];
            acc = fmaf(v0, x0, acc);
            acc = fmaf(v1, x1, acc);
            acc = fmaf(v2, x2, acc);
            acc = fmaf(v3, x3, acc);
        }
        for (; j < n; ++j) {
            int   r = __shfl(er, j);
            float v = __shfl(ev, j);
            acc = fmaf(v, hp[(size_t)r * OU_F + lane], acc);
        }
    }
    out[(size_t)wid * OU_F + lane] = acc;
}

// ---------------- fallback (round-1 atomic scatter) ----------------
__global__ void __launch_bounds__(256)
scatter_kernel(const float* __restrict__ hp, const int* __restrict__ row,
               const int* __restrict__ col, const float* __restrict__ vals,
               float* __restrict__ out, int E)
{
    unsigned int gid = blockIdx.x * 256u + threadIdx.x;
    int e = (int)(gid >> 6);
    if (e >= E) return;
    int f = (int)(gid & 63u);
    int r = row[e], c = col[e];
    float m = vals[e] * hp[(size_t)r * OU_F + f];
    __hip_atomic_fetch_add(&out[(size_t)c * OU_F + f], m,
                           __ATOMIC_RELAXED, __HIP_MEMORY_SCOPE_AGENT);
}

extern "C" void kernel_launch(void* const* d_in, const int* in_sizes, int n_in,
                              void* d_out, int out_size, void* d_ws, size_t ws_size,
                              hipStream_t stream)
{
    const float* h    = (const float*)d_in[0];
    const float* W    = (const float*)d_in[1];
    const int*   row  = (const int*)d_in[2];
    const int*   col  = (const int*)d_in[3];
    const float* vals = (const float*)d_in[4];
    float*       out  = (float*)d_out;

    const int N = in_sizes[0] / IN_F;
    const int E = in_sizes[2];

    char*  ws  = (char*)d_ws;
    size_t off = 0;
    auto alloc = [&](size_t bytes) -> char* {
        char* p = ws + off;
        off = (off + bytes + 255) & ~(size_t)255;
        return p;
    };
    float* hp     = (float*)alloc((size_t)N * OU_F * 4);
    int*   cnt    = (int*)  alloc((size_t)N * 4);
    int*   offs   = (int*)  alloc((size_t)(N + 1) * 4);
    int*   cursor = (int*)  alloc((size_t)N * 4);
    int*   part   = (int*)  alloc(4096);
    int*   erow   = (int*)  alloc((size_t)E * 4);
    float* eval_  = (float*)alloc((size_t)E * 4);
    const bool fits = (off <= ws_size);

    gemm_kernel<<<1024, 256, 0, stream>>>(h, W, hp, N);

    if (fits) {
        hipMemsetAsync(cnt, 0, (size_t)N * 4, stream);
        hist_kernel<<<2048, 256, 0, stream>>>(col, cnt, E);
        int nb = (N + 1023) / 1024;
        scanA_kernel<<<nb, 256, 0, stream>>>(cnt, part, N);
        scanB_kernel<<<1, 64, 0, stream>>>(part, offs, nb, N, E);
        scanC_kernel<<<nb, 256, 0, stream>>>(cnt, part, offs, cursor, N);
        fill_kernel<<<2048, 256, 0, stream>>>(row, col, vals, cursor, erow, eval_, E);
        gather_kernel<<<(N + 3) / 4, 256, 0, stream>>>(hp, offs, erow, eval_, out, N);
    } else {
        hipMemsetAsync(d_out, 0, (size_t)out_size * sizeof(float), stream);
        unsigned long long total = (unsigned long long)E * 64ull;
        unsigned int sgrid = (unsigned int)((total + 255ull) / 256ull);
        scatter_kernel<<<sgrid, 256, 0, stream>>>(hp, row, col, vals, out, E);
    }
}